// Round 7
// baseline (547.964 us; speedup 1.0000x reference)
//
#include <hip/hip_runtime.h>
#include <stdint.h>
#include <stddef.h>

#define B_ 2
#define T_ 2048
#define C_ 1024
#define H_ 16
#define N_ 64
#define M_ (B_*T_)
#define L_ 128              // chunk length
#define NC_ (T_/L_)         // 16 chunks

typedef unsigned short ushort_t;
typedef __attribute__((ext_vector_type(8))) __bf16 bf16x8;
typedef __attribute__((ext_vector_type(4))) float  f32x4;

__device__ __forceinline__ ushort_t f2bf(float x){
  uint32_t u = __float_as_uint(x);
  u += 0x7fffu + ((u >> 16) & 1u);   // RNE to bf16 (inputs finite)
  return (ushort_t)(u >> 16);
}
__device__ __forceinline__ float bf2f(uint32_t hu){
  return __uint_as_float(hu << 16);
}
// load 16 bf16 from LDS (32B) -> 16 f32, two uint4 reads
__device__ __forceinline__ void ldbf16x16(const ushort_t* p, float* o){
  uint4 u0 = *(const uint4*)p;
  uint4 u1 = *(const uint4*)(p+8);
  o[0]=bf2f(u0.x&0xffffu); o[1]=bf2f(u0.x>>16);
  o[2]=bf2f(u0.y&0xffffu); o[3]=bf2f(u0.y>>16);
  o[4]=bf2f(u0.z&0xffffu); o[5]=bf2f(u0.z>>16);
  o[6]=bf2f(u0.w&0xffffu); o[7]=bf2f(u0.w>>16);
  o[8]=bf2f(u1.x&0xffffu); o[9]=bf2f(u1.x>>16);
  o[10]=bf2f(u1.y&0xffffu); o[11]=bf2f(u1.y>>16);
  o[12]=bf2f(u1.z&0xffffu); o[13]=bf2f(u1.z>>16);
  o[14]=bf2f(u1.w&0xffffu); o[15]=bf2f(u1.w>>16);
}

// ---------------- merged prep: activations + weights + missT ----------------
__device__ __forceinline__ ushort4 mixq4(float4 a, float4 p, float4 c){
  ushort4 o;
  o.x = f2bf(fmaf(p.x - a.x, c.x, a.x));
  o.y = f2bf(fmaf(p.y - a.y, c.y, a.y));
  o.z = f2bf(fmaf(p.z - a.z, c.z, a.z));
  o.w = f2bf(fmaf(p.w - a.w, c.w, a.w));
  return o;
}
__global__ __launch_bounds__(256) void prep_all(
    const float* __restrict__ x, const float* __restrict__ x0,
    const float* __restrict__ dx0,
    const float* __restrict__ xq, const float* __restrict__ xk,
    const float* __restrict__ xv,
    const float* __restrict__ Wq, const float* __restrict__ Wk,
    const float* __restrict__ Wv, const float* __restrict__ Wp,
    const float* __restrict__ miss,
    ushort_t* __restrict__ Aq, ushort_t* __restrict__ Ak,
    ushort_t* __restrict__ Av, ushort_t* __restrict__ Axf,
    ushort_t* __restrict__ Xb,
    ushort_t* __restrict__ Wb, ushort_t* __restrict__ Wpb,
    ushort_t* __restrict__ missT)
{
  __shared__ ushort_t tile[128][66];
  const int blk = blockIdx.x;
  const int tid = threadIdx.x;
  if (blk < 4096){
    const int idx = blk*256 + tid;
    const int col4 = idx & 255;
    const int i = idx >> 8;
    const int t = i & (T_-1);
    float4 a = ((const float4*)x)[idx];
    float4 p = {0.f,0.f,0.f,0.f};
    if (t > 0) p = ((const float4*)x)[idx - 256];
    float4 cq = ((const float4*)xq)[col4];
    float4 ck = ((const float4*)xk)[col4];
    float4 cv = ((const float4*)xv)[col4];
    ((ushort4*)Aq)[idx] = mixq4(a, p, cq);
    ((ushort4*)Ak)[idx] = mixq4(a, p, ck);
    ((ushort4*)Av)[idx] = mixq4(a, p, cv);
    float4 z = ((const float4*)x0)[idx];
    float4 d = ((const float4*)dx0)[idx];
    ushort4 of;
    of.x = f2bf(fmaf(d.x, cv.x, z.x));
    of.y = f2bf(fmaf(d.y, cv.y, z.y));
    of.z = f2bf(fmaf(d.z, cv.z, z.z));
    of.w = f2bf(fmaf(d.w, cv.w, z.w));
    ((ushort4*)Axf)[idx] = of;
    ushort4 ob = {f2bf(a.x), f2bf(a.y), f2bf(a.z), f2bf(a.w)};
    ((ushort4*)Xb)[idx] = ob;
  } else if (blk < 4096 + 5*1024){
    const int y = (blk - 4096) >> 10;
    const float* src = (y==0)?Wq:(y==1)?Wk:(y<4)?Wv:Wp;
    ushort_t* dst = (y<4) ? Wb + (size_t)y*C_*C_ : Wpb;
    const int idx = ((blk - 4096) & 1023)*256 + tid;
    float4 v = ((const float4*)src)[idx];
    ushort4 o = {f2bf(v.x), f2bf(v.y), f2bf(v.z), f2bf(v.w)};
    ((ushort4*)dst)[idx] = o;
  } else {
    const int j0 = (blk - 4096 - 5*1024)*64;
#pragma unroll
    for (int rep=0; rep<8; rep++){
      int k = rep*16 + (tid>>4);
      int jj = (tid&15)*4;
      float4 v = *(const float4*)&miss[(size_t)k*4096 + j0 + jj];
      tile[k][jj+0]=f2bf(v.x); tile[k][jj+1]=f2bf(v.y);
      tile[k][jj+2]=f2bf(v.z); tile[k][jj+3]=f2bf(v.w);
    }
    __syncthreads();
#pragma unroll
    for (int rep=0; rep<8; rep++){
      int j = tid>>2;
      int kk = (tid&3)*32 + rep*4;
      ushort4 o = {tile[kk+0][j], tile[kk+1][j], tile[kk+2][j], tile[kk+3][j]};
      *(ushort4*)&missT[(size_t)(j0+j)*128 + kk] = o;
    }
  }
}

// ---------------- bf16 MFMA GEMM (m97 structure) ----------------
__global__ __launch_bounds__(256, 2) void mfma_gemm(
    const ushort_t* __restrict__ Ab, int lda, int64_t Asz,
    const ushort_t* __restrict__ Bbp, int ldb, int64_t Bsz,
    void* __restrict__ Cb, int ldc, int64_t Csz, int c_bf16,
    const float* __restrict__ resid, int K)
{
  const ushort_t* A  = Ab  + (size_t)blockIdx.z * Asz;
  const ushort_t* Bm = Bbp + (size_t)blockIdx.z * Bsz;
  const int i0 = blockIdx.y * 128;
  const int j0 = blockIdx.x * 128;
  const int tid = threadIdx.x;
  const int lane = tid & 63;
  const int w = tid >> 6;
  const int wm = w & 1, wn = w >> 1;

  __shared__ ushort_t As[128*32];
  __shared__ ushort_t Bs[128*32];

  f32x4 acc[4][4];
#pragma unroll
  for (int i=0;i<4;i++)
#pragma unroll
    for (int j=0;j<4;j++) acc[i][j] = (f32x4){0.f,0.f,0.f,0.f};

  const int lr = lane >> 2;
  const int ls = lane & 3;
  const ushort_t* ga = A  + (size_t)(i0 + w*32 + lr)*lda + ls*8;
  const ushort_t* gb = Bm + (size_t)(j0 + w*32 + lr)*ldb + ls*8;
  const int lm = lane & 15, lq = lane >> 4;

  for (int k0 = 0; k0 < K; k0 += 32){
    __syncthreads();
#pragma unroll
    for (int p=0;p<2;p++){
      __builtin_amdgcn_global_load_lds(
        (const __attribute__((address_space(1))) void*)(ga + (size_t)p*16*lda + k0),
        (__attribute__((address_space(3))) void*)&As[(w*32 + p*16)*32], 16, 0, 0);
      __builtin_amdgcn_global_load_lds(
        (const __attribute__((address_space(1))) void*)(gb + (size_t)p*16*ldb + k0),
        (__attribute__((address_space(3))) void*)&Bs[(w*32 + p*16)*32], 16, 0, 0);
    }
    __syncthreads();
    bf16x8 af[4], bfr[4];
#pragma unroll
    for (int i=0;i<4;i++)
      af[i] = *(const bf16x8*)&As[(wm*64 + i*16 + lm)*32 + lq*8];
#pragma unroll
    for (int j=0;j<4;j++)
      bfr[j] = *(const bf16x8*)&Bs[(wn*64 + j*16 + lm)*32 + lq*8];
#pragma unroll
    for (int i=0;i<4;i++)
#pragma unroll
      for (int j=0;j<4;j++)
        acc[i][j] = __builtin_amdgcn_mfma_f32_16x16x32_bf16(af[i], bfr[j], acc[i][j], 0, 0, 0);
  }

  if (!c_bf16){
    float* C = (float*)Cb + (size_t)blockIdx.z * Csz;
#pragma unroll
    for (int i=0;i<4;i++)
#pragma unroll
      for (int j=0;j<4;j++)
#pragma unroll
        for (int r=0;r<4;r++){
          const int row = i0 + wm*64 + i*16 + lq*4 + r;
          const int col = j0 + wn*64 + j*16 + lm;
          float v = acc[i][j][r];
          if (resid) v += resid[(size_t)row*ldc + col];
          C[(size_t)row*ldc + col] = v;
        }
  } else {
    ushort_t* C = (ushort_t*)Cb + (size_t)blockIdx.z * Csz;
#pragma unroll
    for (int i=0;i<4;i++)
#pragma unroll
      for (int j=0;j<4;j++)
#pragma unroll
        for (int r=0;r<4;r++){
          const int row = i0 + wm*64 + i*16 + lq*4 + r;
          const int col = j0 + wn*64 + j*16 + lm;
          C[(size_t)row*ldc + col] = f2bf(acc[i][j][r]);
        }
  }
}

// ---------------- fused elementwise + head norms + bf16 pack ----------------
__global__ __launch_bounds__(256) void fuse_kernel(
    const float* __restrict__ qm, const float* __restrict__ km,
    const float* __restrict__ vm, const float* __restrict__ vfm,
    const ushort_t* __restrict__ del, const float* __restrict__ x,
    const float* __restrict__ w0, const float* __restrict__ v0,
    const float* __restrict__ a0,
    uint32_t* __restrict__ packed, float* __restrict__ gout,
    float* __restrict__ ratio)
{
  const int lane = threadIdx.x & 63;
  const int ht = blockIdx.x*4 + (threadIdx.x >> 6);
  const int i = ht >> 4;
  const int h = ht & 15;
  const int c = h*64 + lane;
  const size_t ic = (size_t)i*C_ + c;
  float qv = qm[ic], kv = km[ic], vv = vm[ic], vfv = vfm[ic], xv = x[ic];
  const size_t d0 = (size_t)i*4*C_ + c;
  float wd = bf2f(del[d0]), vd = bf2f(del[d0+C_]);
  float ad = bf2f(del[d0+2*C_]), gd = bf2f(del[d0+3*C_]);

  float z1 = -(w0[c]+wd);
  float sp = fmaxf(z1, 0.f) + log1pf(expf(-fabsf(z1)));
  float logw = -expf(-sp - 0.5f);
  float sv = 1.f/(1.f+expf(-(v0[c]+vd)));
  vv = vv + (vfv - vv)*sv;
  float gv = 1.f + gd;
  float av = 1.f/(1.f+expf(-(a0[c]+ad)));

  ushort_t vr_u = f2bf(vv);
  float vrf = bf2f(vr_u);

  float ksq = kv*kv, xsq = xv*xv, vsq = vrf*vrf;
#pragma unroll
  for (int off=32; off>0; off>>=1){
    ksq += __shfl_xor(ksq, off, 64);
    xsq += __shfl_xor(xsq, off, 64);
    vsq += __shfl_xor(vsq, off, 64);
  }
  float kn = sqrtf(ksq);
  float kkn = kv / fmaxf(kn, 1e-12f);
  float k2 = kv*av;
  float zv = -kkn;
  float bv = kkn*av;

  uint32_t p0 = (uint32_t)f2bf(logw) | ((uint32_t)f2bf(zv) << 16);
  uint32_t p1 = (uint32_t)f2bf(bv)   | ((uint32_t)f2bf(k2) << 16);
  uint32_t p2 = (uint32_t)f2bf(qv)   | ((uint32_t)vr_u << 16);
  uint32_t* pb = packed + ((size_t)ht*64 + lane)*3;
  pb[0]=p0; pb[1]=p1; pb[2]=p2;
  gout[ic] = gv;
  if (lane == 0)
    ratio[ht] = 1.f - sqrtf(xsq)/(sqrtf(vsq)+1e-12f);
}

// ================= chunked scan =================
// S_t = S_{t-1}*M_t + v_t k_t^T,  M_t = diag(ew_t) + z_t b_t^T.
// Per chunk: Phi_t prefix (X from I), C_t prefix (Z from 0);
// m_t = Phi_t q_t, d_t = C_t q_t  =>  o_t = S_start m_t + d_t.

// ---- pass 1 (combined X+Z, bf16 LDS operands). thread=(rp row, qr k-quarter)
__global__ __launch_bounds__(256) void chunk_mdp_kernel(
    const uint32_t* __restrict__ packed,
    float* __restrict__ phi, float* __restrict__ cc, float* __restrict__ md)
{
  const int blk = blockIdx.x;          // bh*NC_ + c
  const int c  = blk & (NC_-1);
  const int bh = blk >> 4;             // NC_ == 16
  const int b = bh >> 4, h = bh & 15;
  const int tid = threadIdx.x;
  const int rp = tid >> 2;
  const int qr = tid & 3;
  const int t0 = c * L_;

  __shared__ float    ewS[4][N_], vS[4][N_];
  __shared__ ushort_t zS[4][N_], bS[4][N_], qS[4][N_], kS[4][N_];

  float X[16], Z[16];
#pragma unroll
  for (int i=0;i<16;i++){ X[i] = (qr*16+i == rp) ? 1.f : 0.f; Z[i] = 0.f; }

  const int s = tid >> 6, d = tid & 63;
  size_t ap = (((size_t)(b*T_+t0+s))*H_ + h)*64 + d;
  uint32_t pu0 = packed[ap*3], pu1 = packed[ap*3+1], pu2 = packed[ap*3+2];

  for (int tg = 0; tg < L_; tg += 4){
    __syncthreads();                       // prev group's readers done
    ewS[s][d] = __expf(bf2f(pu0 & 0xffffu));
    zS[s][d]  = (ushort_t)(pu0 >> 16);
    bS[s][d]  = (ushort_t)(pu1 & 0xffffu);
    kS[s][d]  = (ushort_t)(pu1 >> 16);
    qS[s][d]  = (ushort_t)(pu2 & 0xffffu);
    vS[s][d]  = bf2f(pu2 >> 16);
    if (tg + 4 < L_){
      size_t a2 = (((size_t)(b*T_+t0+tg+4+s))*H_ + h)*64 + d;
      pu0 = packed[a2*3]; pu1 = packed[a2*3+1]; pu2 = packed[a2*3+2];
    }
    __syncthreads();                       // group visible
#pragma unroll 1
    for (int ss=0; ss<4; ss++){
      float zf[16], ef[16], bf[16], qf[16], kf[16];
      ldbf16x16(&zS[ss][qr*16], zf);
      ldbf16x16(&bS[ss][qr*16], bf);
      ldbf16x16(&qS[ss][qr*16], qf);
      ldbf16x16(&kS[ss][qr*16], kf);
#pragma unroll
      for (int i4=0;i4<4;i4++)
        *(float4*)&ef[i4*4] = *(const float4*)&ewS[ss][qr*16+i4*4];
      const float vr = vS[ss][rp];
      float a0=0.f,a1=0.f,a2=0.f,a3=0.f, c0=0.f,c1=0.f,c2=0.f,c3=0.f;
#pragma unroll
      for (int i=0;i<16;i+=4){
        a0 = fmaf(X[i+0], zf[i+0], a0); a1 = fmaf(X[i+1], zf[i+1], a1);
        a2 = fmaf(X[i+2], zf[i+2], a2); a3 = fmaf(X[i+3], zf[i+3], a3);
        c0 = fmaf(Z[i+0], zf[i+0], c0); c1 = fmaf(Z[i+1], zf[i+1], c1);
        c2 = fmaf(Z[i+2], zf[i+2], c2); c3 = fmaf(Z[i+3], zf[i+3], c3);
      }
      float sx = (a0+a1)+(a2+a3);
      float sz = (c0+c1)+(c2+c3);
      sx += __shfl_xor(sx,1,64); sx += __shfl_xor(sx,2,64);
      sz += __shfl_xor(sz,1,64); sz += __shfl_xor(sz,2,64);
      float m0=0.f,m1=0.f,m2=0.f,m3=0.f, d0=0.f,d1=0.f,d2=0.f,d3=0.f;
#pragma unroll
      for (int i=0;i<16;i+=4){
        float t;
        t = fmaf(X[i+0], ef[i+0], sx*bf[i+0]); X[i+0]=t; m0 = fmaf(t, qf[i+0], m0);
        t = fmaf(X[i+1], ef[i+1], sx*bf[i+1]); X[i+1]=t; m1 = fmaf(t, qf[i+1], m1);
        t = fmaf(X[i+2], ef[i+2], sx*bf[i+2]); X[i+2]=t; m2 = fmaf(t, qf[i+2], m2);
        t = fmaf(X[i+3], ef[i+3], sx*bf[i+3]); X[i+3]=t; m3 = fmaf(t, qf[i+3], m3);
        t = fmaf(Z[i+0], ef[i+0], fmaf(sz, bf[i+0], vr*kf[i+0])); Z[i+0]=t; d0 = fmaf(t, qf[i+0], d0);
        t = fmaf(Z[i+1], ef[i+1], fmaf(sz, bf[i+1], vr*kf[i+1])); Z[i+1]=t; d1 = fmaf(t, qf[i+1], d1);
        t = fmaf(Z[i+2], ef[i+2], fmaf(sz, bf[i+2], vr*kf[i+2])); Z[i+2]=t; d2 = fmaf(t, qf[i+2], d2);
        t = fmaf(Z[i+3], ef[i+3], fmaf(sz, bf[i+3], vr*kf[i+3])); Z[i+3]=t; d3 = fmaf(t, qf[i+3], d3);
      }
      float mv = (m0+m1)+(m2+m3);
      float dv = (d0+d1)+(d2+d3);
      mv += __shfl_xor(mv,1,64); mv += __shfl_xor(mv,2,64);
      dv += __shfl_xor(dv,1,64); dv += __shfl_xor(dv,2,64);
      if (qr == 0)      md[((size_t)blk*L_ + tg+ss)*128 + rp]      = mv;
      else if (qr == 1) md[((size_t)blk*L_ + tg+ss)*128 + 64 + rp] = dv;
    }
  }
  const size_t base = (size_t)blk*4096 + (size_t)rp*64 + qr*16;
#pragma unroll
  for (int i4=0;i4<4;i4++){
    float4 xo = {X[i4*4+0],X[i4*4+1],X[i4*4+2],X[i4*4+3]};
    float4 zo = {Z[i4*4+0],Z[i4*4+1],Z[i4*4+2],Z[i4*4+3]};
    *(float4*)&phi[base + i4*4] = xo;
    *(float4*)&cc [base + i4*4] = zo;
  }
}

// ---- pass 2: sequential chunk combine per (b,h), phi+cc both prefetched
__global__ __launch_bounds__(256) void chunk_state_kernel(
    const float* __restrict__ phi, const float* __restrict__ cc,
    float* __restrict__ sstart)
{
  const int bh = blockIdx.x;
  const int tid = threadIdx.x;
  const int rb = tid >> 4;
  const int cq = tid & 15;
  __shared__ float Sld[64][65];
  __shared__ float Fld[64][68];
  float acc[4][4];
#pragma unroll
  for (int m=0;m<4;m++)
#pragma unroll
    for (int i=0;i<4;i++) acc[m][i] = 0.f;
#pragma unroll
  for (int m=0;m<4;m++){
    float4 z4 = {0.f,0.f,0.f,0.f};
    *(float4*)&Sld[rb+16*m][cq*4] = z4;
  }
  const float* pc = phi + (size_t)bh*NC_*4096;
  const float* cb = cc  + (size_t)bh*NC_*4096;
  float4 pf[4], pcc[4];
#pragma unroll
  for (int p=0;p<4;p++) pf[p] = *(const float4*)&pc[(size_t)p*1024 + tid*4];
#pragma unroll
  for (int m=0;m<4;m++) pcc[m] = *(const float4*)&cb[(size_t)(rb+16*m)*64 + cq*4];

  for (int c=0;c<NC_;c++){
    __syncthreads();
#pragma unroll
    for (int p=0;p<4;p++){
      int f = p*1024 + tid*4;
      *(float4*)&Fld[f>>6][f&63] = pf[p];
    }
    float na[4][4];
#pragma unroll
    for (int m=0;m<4;m++){
      na[m][0]=pcc[m].x; na[m][1]=pcc[m].y; na[m][2]=pcc[m].z; na[m][3]=pcc[m].w;
    }
#pragma unroll
    for (int m=0;m<4;m++){
      float4 so = {acc[m][0],acc[m][1],acc[m][2],acc[m][3]};
      *(float4*)&sstart[(size_t)(bh*NC_+c)*4096 + (size_t)(rb+16*m)*64 + cq*4] = so;
    }
    if (c+1 < NC_){
#pragma unroll
      for (int p=0;p<4;p++) pf[p] = *(const float4*)&pc[(size_t)(c+1)*4096 + p*1024 + tid*4];
#pragma unroll
      for (int m=0;m<4;m++) pcc[m] = *(const float4*)&cb[(size_t)(c+1)*4096 + (size_t)(rb+16*m)*64 + cq*4];
    }
    __syncthreads();
#pragma unroll 1
    for (int k0=0;k0<64;k0+=4){
      float4 sr[4];
#pragma unroll
      for (int m=0;m<4;m++) sr[m] = *(const float4*)&Sld[rb+16*m][k0];
      const float4 f0 = *(const float4*)&Fld[k0+0][cq*4];
      const float4 f1 = *(const float4*)&Fld[k0+1][cq*4];
      const float4 f2 = *(const float4*)&Fld[k0+2][cq*4];
      const float4 f3 = *(const float4*)&Fld[k0+3][cq*4];
#pragma unroll
      for (int m=0;m<4;m++){
        na[m][0] = fmaf(sr[m].x, f0.x, na[m][0]); na[m][0] = fmaf(sr[m].y, f1.x, na[m][0]);
        na[m][0] = fmaf(sr[m].z, f2.x, na[m][0]); na[m][0] = fmaf(sr[m].w, f3.x, na[m][0]);
        na[m][1] = fmaf(sr[m].x, f0.y, na[m][1]); na[m][1] = fmaf(sr[m].y, f1.y, na[m][1]);
        na[m][1] = fmaf(sr[m].z, f2.y, na[m][1]); na[m][1] = fmaf(sr[m].w, f3.y, na[m][1]);
        na[m][2] = fmaf(sr[m].x, f0.z, na[m][2]); na[m][2] = fmaf(sr[m].y, f1.z, na[m][2]);
        na[m][2] = fmaf(sr[m].z, f2.z, na[m][2]); na[m][2] = fmaf(sr[m].w, f3.z, na[m][2]);
        na[m][3] = fmaf(sr[m].x, f0.w, na[m][3]); na[m][3] = fmaf(sr[m].y, f1.w, na[m][3]);
        na[m][3] = fmaf(sr[m].z, f2.w, na[m][3]); na[m][3] = fmaf(sr[m].w, f3.w, na[m][3]);
      }
    }
    __syncthreads();
#pragma unroll
    for (int m=0;m<4;m++){
      float4 so = {na[m][0],na[m][1],na[m][2],na[m][3]};
      *(float4*)&Sld[rb+16*m][cq*4] = so;
#pragma unroll
      for (int i=0;i<4;i++) acc[m][i] = na[m][i];
    }
  }
}

// ---- pass 3: o = S_start·m + d, epilogue, emit bf16 y
__global__ __launch_bounds__(256) void chunk_emit_kernel(
    const uint32_t* __restrict__ packed, const float* __restrict__ ratio,
    const float* __restrict__ g, const float* __restrict__ rk,
    const float* __restrict__ sstart, const float* __restrict__ md,
    ushort_t* __restrict__ y)
{
  const int blk = blockIdx.x;
  const int c  = blk & (NC_-1);
  const int bh = blk >> 4;
  const int b = bh >> 4, h = bh & 15;
  const int tid = threadIdx.x;
  const int v = tid & 63;
  const int tg = tid >> 6;

  float4 sr[16];
  const float4* sp = (const float4*)(sstart + (size_t)blk*4096 + (size_t)v*64);
#pragma unroll
  for (int f=0;f<16;f++) sr[f] = sp[f];
  const float sigrk = 1.f/(1.f+__expf(-rk[h*64+v]));

#pragma unroll 1
  for (int ss=0; ss<32; ss++){
    const int t = tg*32 + ss;
    const int token = b*T_ + c*L_ + t;
    const float* mrow = md + ((size_t)blk*L_ + t)*128;
    float o0=0.f,o1=0.f,o2=0.f,o3=0.f;
#pragma unroll
    for (int f=0;f<16;f+=4){
      float4 m0 = ((const float4*)mrow)[f+0];
      float4 m1 = ((const float4*)mrow)[f+1];
      float4 m2 = ((const float4*)mrow)[f+2];
      float4 m3 = ((const float4*)mrow)[f+3];
      o0 = fmaf(sr[f+0].x,m0.x, fmaf(sr[f+0].y,m0.y, fmaf(sr[f+0].z,m0.z, fmaf(sr[f+0].w,m0.w, o0))));
      o1 = fmaf(sr[f+1].x,m1.x, fmaf(sr[f+1].y,m1.y, fmaf(sr[f+1].z,m1.z, fmaf(sr[f+1].w,m1.w, o1))));
      o2 = fmaf(sr[f+2].x,m2.x, fmaf(sr[f+2].y,m2.y, fmaf(sr[f+2].z,m2.z, fmaf(sr[f+2].w,m2.w, o2))));
      o3 = fmaf(sr[f+3].x,m3.x, fmaf(sr[f+3].y,m3.y, fmaf(sr[f+3].z,m3.z, fmaf(sr[f+3].w,m3.w, o3))));
    }
    float o = ((o0+o1)+(o2+o3)) + mrow[64 + v];
    const float vt = bf2f(packed[(((size_t)token*H_ + h)*64 + v)*3 + 2] >> 16);
    const float uv = ratio[(size_t)token*H_ + h];
    const float gv = g[(size_t)token*C_ + h*64 + v];
    y[(size_t)token*C_ + h*64 + v] = f2bf((o*0.125f + vt*uv*sigrk)*gv);
  }
}

extern "C" void kernel_launch(void* const* d_in, const int* in_sizes, int n_in,
                              void* d_out, int out_size, void* d_ws, size_t ws_size,
                              hipStream_t stream)
{
  const float* residual = (const float*)d_in[0];
  const float* x    = (const float*)d_in[1];
  const float* x0   = (const float*)d_in[2];
  const float* dx0  = (const float*)d_in[3];
  const float* Wq   = (const float*)d_in[4];
  const float* Wk   = (const float*)d_in[5];
  const float* Wv   = (const float*)d_in[6];
  const float* Wpr  = (const float*)d_in[7];
  const float* x_q  = (const float*)d_in[8];
  const float* x_k  = (const float*)d_in[9];
  const float* x_v  = (const float*)d_in[10];
  const float* v0   = (const float*)d_in[11];
  const float* w0   = (const float*)d_in[12];
  const float* a0   = (const float*)d_in[13];
  const float* miss = (const float*)d_in[14];
  const float* rk   = (const float*)d_in[15];
  float* out = (float*)d_out;

  char* ws = (char*)d_ws;
  const size_t MB = (size_t)1 << 20;
  // phase A (pre-fuse):
  float*    q_m    = (float*)(ws + 0*MB);      // [0,64): q,k,v,vf f32
  float*    k_m    = (float*)(ws + 16*MB);
  float*    v_m    = (float*)(ws + 32*MB);
  float*    vf_m   = (float*)(ws + 48*MB);
  ushort_t* delb   = (ushort_t*)(ws + 64*MB);  // [64,96) bf16 deltas
  ushort_t* Ab     = (ushort_t*)(ws + 96*MB);  // [96,128): Aq,Ak,Av,Axf
  ushort_t* Xb     = (ushort_t*)(ws + 128*MB); // [128,136)
  ushort_t* Wb     = (ushort_t*)(ws + 136*MB); // [136,144): Wq,Wk,Wv,Wv
  // phase B (fuse onward):
  uint32_t* packed = (uint32_t*)(ws + 96*MB);  // [96,144) overlay Ab/Xb/Wb
  float*    g_m    = (float*)(ws + 144*MB);    // [144,160)
  ushort_t* Wpb    = (ushort_t*)(ws + 160*MB); // [160,162)
  ushort_t* missT  = (ushort_t*)(ws + 162*MB); // [162,163)
  float*    ratio  = (float*)(ws + 163*MB);    // 256KB
  // phase C (post-fuse, overlay dead q/k/v/vf + delb):
  float*    phi    = (float*)(ws + 0*MB);      // [0,8)
  float*    cc     = (float*)(ws + 16*MB);     // [16,24)
  float*    sstart = (float*)(ws + 32*MB);     // [32,40)
  ushort_t* yb     = (ushort_t*)(ws + 48*MB);  // [48,56) overlay vf_m
  float*    mdbuf  = (float*)(ws + 64*MB);     // [64,96) overlay delb

  ushort_t* Aq  = Ab + 0*(size_t)M_*C_;
  ushort_t* Ak  = Ab + 1*(size_t)M_*C_;
  ushort_t* Av  = Ab + 2*(size_t)M_*C_;
  ushort_t* Axf = Ab + 3*(size_t)M_*C_;

  dim3 blk(256);
  prep_all<<<4096 + 5*1024 + 64, blk, 0, stream>>>(
      x, x0, dx0, x_q, x_k, x_v, Wq, Wk, Wv, Wpr, miss,
      Aq, Ak, Av, Axf, Xb, Wb, Wpb, missT);
  mfma_gemm<<<dim3(C_/128, M_/128, 4), blk, 0, stream>>>(
      Ab, C_, (int64_t)M_*C_, Wb, C_, (int64_t)C_*C_,
      q_m, C_, (int64_t)M_*C_, 0, nullptr, C_);
  mfma_gemm<<<dim3(4*C_/128, M_/128, 1), blk, 0, stream>>>(
      Xb, C_, 0, missT, 128, 0, delb, 4*C_, 0, 1, nullptr, 128);
  fuse_kernel<<<M_*H_/4, blk, 0, stream>>>(q_m, k_m, v_m, vf_m, delb, x, w0, v0, a0, packed, g_m, ratio);
  chunk_mdp_kernel<<<B_*H_*NC_, blk, 0, stream>>>(packed, phi, cc, mdbuf);
  chunk_state_kernel<<<B_*H_, blk, 0, stream>>>(phi, cc, sstart);
  chunk_emit_kernel<<<B_*H_*NC_, blk, 0, stream>>>(packed, ratio, g_m, rk, sstart, mdbuf, yb);
  mfma_gemm<<<dim3(C_/128, M_/128, 1), blk, 0, stream>>>(
      yb, C_, 0, Wpb, C_, 0, out, C_, 0, 0, residual, C_);
}

// Round 8
// 529.835 us; speedup vs baseline: 1.0342x; 1.0342x over previous
//
#include <hip/hip_runtime.h>
#include <stdint.h>
#include <stddef.h>

#define B_ 2
#define T_ 2048
#define C_ 1024
#define H_ 16
#define N_ 64
#define M_ (B_*T_)
#define L_ 128              // chunk length
#define NC_ (T_/L_)         // 16 chunks

typedef unsigned short ushort_t;
typedef __attribute__((ext_vector_type(8))) __bf16 bf16x8;
typedef __attribute__((ext_vector_type(4))) float  f32x4;

__device__ __forceinline__ ushort_t f2bf(float x){
  uint32_t u = __float_as_uint(x);
  u += 0x7fffu + ((u >> 16) & 1u);   // RNE to bf16 (inputs finite)
  return (ushort_t)(u >> 16);
}
__device__ __forceinline__ float bf2f(uint32_t hu){
  return __uint_as_float(hu << 16);
}
// load 16 bf16 from LDS (32B) -> 16 f32, two uint4 reads
__device__ __forceinline__ void ldbf16x16(const ushort_t* p, float* o){
  uint4 u0 = *(const uint4*)p;
  uint4 u1 = *(const uint4*)(p+8);
  o[0]=bf2f(u0.x&0xffffu); o[1]=bf2f(u0.x>>16);
  o[2]=bf2f(u0.y&0xffffu); o[3]=bf2f(u0.y>>16);
  o[4]=bf2f(u0.z&0xffffu); o[5]=bf2f(u0.z>>16);
  o[6]=bf2f(u0.w&0xffffu); o[7]=bf2f(u0.w>>16);
  o[8]=bf2f(u1.x&0xffffu); o[9]=bf2f(u1.x>>16);
  o[10]=bf2f(u1.y&0xffffu); o[11]=bf2f(u1.y>>16);
  o[12]=bf2f(u1.z&0xffffu); o[13]=bf2f(u1.z>>16);
  o[14]=bf2f(u1.w&0xffffu); o[15]=bf2f(u1.w>>16);
}
// sum across 4-lane quad via DPP (VALU pipe, not ds_swizzle)
__device__ __forceinline__ float quad_sum(float v){
  float a = __int_as_float(__builtin_amdgcn_mov_dpp(__float_as_int(v), 0xB1, 0xF, 0xF, true)); // xor 1
  v += a;
  float b = __int_as_float(__builtin_amdgcn_mov_dpp(__float_as_int(v), 0x4E, 0xF, 0xF, true)); // xor 2
  return v + b;
}

// ---------------- merged prep: activations + weights + missT ----------------
__device__ __forceinline__ ushort4 mixq4(float4 a, float4 p, float4 c){
  ushort4 o;
  o.x = f2bf(fmaf(p.x - a.x, c.x, a.x));
  o.y = f2bf(fmaf(p.y - a.y, c.y, a.y));
  o.z = f2bf(fmaf(p.z - a.z, c.z, a.z));
  o.w = f2bf(fmaf(p.w - a.w, c.w, a.w));
  return o;
}
__global__ __launch_bounds__(256) void prep_all(
    const float* __restrict__ x, const float* __restrict__ x0,
    const float* __restrict__ dx0,
    const float* __restrict__ xq, const float* __restrict__ xk,
    const float* __restrict__ xv,
    const float* __restrict__ Wq, const float* __restrict__ Wk,
    const float* __restrict__ Wv, const float* __restrict__ Wp,
    const float* __restrict__ miss,
    ushort_t* __restrict__ Aq, ushort_t* __restrict__ Ak,
    ushort_t* __restrict__ Av, ushort_t* __restrict__ Axf,
    ushort_t* __restrict__ Xb,
    ushort_t* __restrict__ Wb, ushort_t* __restrict__ Wpb,
    ushort_t* __restrict__ missT)
{
  __shared__ ushort_t tile[128][66];
  const int blk = blockIdx.x;
  const int tid = threadIdx.x;
  if (blk < 4096){
    const int idx = blk*256 + tid;
    const int col4 = idx & 255;
    const int i = idx >> 8;
    const int t = i & (T_-1);
    float4 a = ((const float4*)x)[idx];
    float4 p = {0.f,0.f,0.f,0.f};
    if (t > 0) p = ((const float4*)x)[idx - 256];
    float4 cq = ((const float4*)xq)[col4];
    float4 ck = ((const float4*)xk)[col4];
    float4 cv = ((const float4*)xv)[col4];
    ((ushort4*)Aq)[idx] = mixq4(a, p, cq);
    ((ushort4*)Ak)[idx] = mixq4(a, p, ck);
    ((ushort4*)Av)[idx] = mixq4(a, p, cv);
    float4 z = ((const float4*)x0)[idx];
    float4 d = ((const float4*)dx0)[idx];
    ushort4 of;
    of.x = f2bf(fmaf(d.x, cv.x, z.x));
    of.y = f2bf(fmaf(d.y, cv.y, z.y));
    of.z = f2bf(fmaf(d.z, cv.z, z.z));
    of.w = f2bf(fmaf(d.w, cv.w, z.w));
    ((ushort4*)Axf)[idx] = of;
    ushort4 ob = {f2bf(a.x), f2bf(a.y), f2bf(a.z), f2bf(a.w)};
    ((ushort4*)Xb)[idx] = ob;
  } else if (blk < 4096 + 5*1024){
    const int y = (blk - 4096) >> 10;
    const float* src = (y==0)?Wq:(y==1)?Wk:(y<4)?Wv:Wp;
    ushort_t* dst = (y<4) ? Wb + (size_t)y*C_*C_ : Wpb;
    const int idx = ((blk - 4096) & 1023)*256 + tid;
    float4 v = ((const float4*)src)[idx];
    ushort4 o = {f2bf(v.x), f2bf(v.y), f2bf(v.z), f2bf(v.w)};
    ((ushort4*)dst)[idx] = o;
  } else {
    const int j0 = (blk - 4096 - 5*1024)*64;
#pragma unroll
    for (int rep=0; rep<8; rep++){
      int k = rep*16 + (tid>>4);
      int jj = (tid&15)*4;
      float4 v = *(const float4*)&miss[(size_t)k*4096 + j0 + jj];
      tile[k][jj+0]=f2bf(v.x); tile[k][jj+1]=f2bf(v.y);
      tile[k][jj+2]=f2bf(v.z); tile[k][jj+3]=f2bf(v.w);
    }
    __syncthreads();
#pragma unroll
    for (int rep=0; rep<8; rep++){
      int j = tid>>2;
      int kk = (tid&3)*32 + rep*4;
      ushort4 o = {tile[kk+0][j], tile[kk+1][j], tile[kk+2][j], tile[kk+3][j]};
      *(ushort4*)&missT[(size_t)(j0+j)*128 + kk] = o;
    }
  }
}

// ---------------- bf16 MFMA GEMM (m97 structure) ----------------
__global__ __launch_bounds__(256, 2) void mfma_gemm(
    const ushort_t* __restrict__ Ab, int lda, int64_t Asz,
    const ushort_t* __restrict__ Bbp, int ldb, int64_t Bsz,
    void* __restrict__ Cb, int ldc, int64_t Csz, int c_bf16,
    const float* __restrict__ resid, int K)
{
  const ushort_t* A  = Ab  + (size_t)blockIdx.z * Asz;
  const ushort_t* Bm = Bbp + (size_t)blockIdx.z * Bsz;
  const int i0 = blockIdx.y * 128;
  const int j0 = blockIdx.x * 128;
  const int tid = threadIdx.x;
  const int lane = tid & 63;
  const int w = tid >> 6;
  const int wm = w & 1, wn = w >> 1;

  __shared__ ushort_t As[128*32];
  __shared__ ushort_t Bs[128*32];

  f32x4 acc[4][4];
#pragma unroll
  for (int i=0;i<4;i++)
#pragma unroll
    for (int j=0;j<4;j++) acc[i][j] = (f32x4){0.f,0.f,0.f,0.f};

  const int lr = lane >> 2;
  const int ls = lane & 3;
  const ushort_t* ga = A  + (size_t)(i0 + w*32 + lr)*lda + ls*8;
  const ushort_t* gb = Bm + (size_t)(j0 + w*32 + lr)*ldb + ls*8;
  const int lm = lane & 15, lq = lane >> 4;

  for (int k0 = 0; k0 < K; k0 += 32){
    __syncthreads();
#pragma unroll
    for (int p=0;p<2;p++){
      __builtin_amdgcn_global_load_lds(
        (const __attribute__((address_space(1))) void*)(ga + (size_t)p*16*lda + k0),
        (__attribute__((address_space(3))) void*)&As[(w*32 + p*16)*32], 16, 0, 0);
      __builtin_amdgcn_global_load_lds(
        (const __attribute__((address_space(1))) void*)(gb + (size_t)p*16*ldb + k0),
        (__attribute__((address_space(3))) void*)&Bs[(w*32 + p*16)*32], 16, 0, 0);
    }
    __syncthreads();
    bf16x8 af[4], bfr[4];
#pragma unroll
    for (int i=0;i<4;i++)
      af[i] = *(const bf16x8*)&As[(wm*64 + i*16 + lm)*32 + lq*8];
#pragma unroll
    for (int j=0;j<4;j++)
      bfr[j] = *(const bf16x8*)&Bs[(wn*64 + j*16 + lm)*32 + lq*8];
#pragma unroll
    for (int i=0;i<4;i++)
#pragma unroll
      for (int j=0;j<4;j++)
        acc[i][j] = __builtin_amdgcn_mfma_f32_16x16x32_bf16(af[i], bfr[j], acc[i][j], 0, 0, 0);
  }

  if (!c_bf16){
    float* C = (float*)Cb + (size_t)blockIdx.z * Csz;
#pragma unroll
    for (int i=0;i<4;i++)
#pragma unroll
      for (int j=0;j<4;j++)
#pragma unroll
        for (int r=0;r<4;r++){
          const int row = i0 + wm*64 + i*16 + lq*4 + r;
          const int col = j0 + wn*64 + j*16 + lm;
          float v = acc[i][j][r];
          if (resid) v += resid[(size_t)row*ldc + col];
          C[(size_t)row*ldc + col] = v;
        }
  } else {
    ushort_t* C = (ushort_t*)Cb + (size_t)blockIdx.z * Csz;
#pragma unroll
    for (int i=0;i<4;i++)
#pragma unroll
      for (int j=0;j<4;j++)
#pragma unroll
        for (int r=0;r<4;r++){
          const int row = i0 + wm*64 + i*16 + lq*4 + r;
          const int col = j0 + wn*64 + j*16 + lm;
          C[(size_t)row*ldc + col] = f2bf(acc[i][j][r]);
        }
  }
}

// ---------------- fused elementwise + head norms + bf16 pack ----------------
__global__ __launch_bounds__(256) void fuse_kernel(
    const float* __restrict__ qm, const float* __restrict__ km,
    const float* __restrict__ vm, const float* __restrict__ vfm,
    const ushort_t* __restrict__ del, const float* __restrict__ x,
    const float* __restrict__ w0, const float* __restrict__ v0,
    const float* __restrict__ a0,
    uint32_t* __restrict__ packed, float* __restrict__ gout,
    float* __restrict__ ratio)
{
  const int lane = threadIdx.x & 63;
  const int ht = blockIdx.x*4 + (threadIdx.x >> 6);
  const int i = ht >> 4;
  const int h = ht & 15;
  const int c = h*64 + lane;
  const size_t ic = (size_t)i*C_ + c;
  float qv = qm[ic], kv = km[ic], vv = vm[ic], vfv = vfm[ic], xv = x[ic];
  const size_t d0 = (size_t)i*4*C_ + c;
  float wd = bf2f(del[d0]), vd = bf2f(del[d0+C_]);
  float ad = bf2f(del[d0+2*C_]), gd = bf2f(del[d0+3*C_]);

  float z1 = -(w0[c]+wd);
  float sp = fmaxf(z1, 0.f) + log1pf(expf(-fabsf(z1)));
  float logw = -expf(-sp - 0.5f);
  float sv = 1.f/(1.f+expf(-(v0[c]+vd)));
  vv = vv + (vfv - vv)*sv;
  float gv = 1.f + gd;
  float av = 1.f/(1.f+expf(-(a0[c]+ad)));

  ushort_t vr_u = f2bf(vv);
  float vrf = bf2f(vr_u);

  float ksq = kv*kv, xsq = xv*xv, vsq = vrf*vrf;
#pragma unroll
  for (int off=32; off>0; off>>=1){
    ksq += __shfl_xor(ksq, off, 64);
    xsq += __shfl_xor(xsq, off, 64);
    vsq += __shfl_xor(vsq, off, 64);
  }
  float kn = sqrtf(ksq);
  float kkn = kv / fmaxf(kn, 1e-12f);
  float k2 = kv*av;
  float zv = -kkn;
  float bv = kkn*av;

  uint32_t p0 = (uint32_t)f2bf(logw) | ((uint32_t)f2bf(zv) << 16);
  uint32_t p1 = (uint32_t)f2bf(bv)   | ((uint32_t)f2bf(k2) << 16);
  uint32_t p2 = (uint32_t)f2bf(qv)   | ((uint32_t)vr_u << 16);
  uint32_t* pb = packed + ((size_t)ht*64 + lane)*3;
  pb[0]=p0; pb[1]=p1; pb[2]=p2;
  gout[ic] = gv;
  if (lane == 0)
    ratio[ht] = 1.f - sqrtf(xsq)/(sqrtf(vsq)+1e-12f);
}

// ================= chunked scan =================
// S_t = S_{t-1}*M_t + v_t k_t^T,  M_t = diag(ew_t) + z_t b_t^T.
// Per chunk: Phi_t prefix (X from I), C_t prefix (Z from 0);
// m_t = Phi_t q_t, d_t = C_t q_t  =>  o_t = S_start m_t + d_t.

// ---- pass 1: 2 chunks/block, thread = (chunk, row-pair, col-quarter)
__global__ __launch_bounds__(256, 1) void chunk_mdp_kernel(
    const uint32_t* __restrict__ packed,
    float* __restrict__ phi, float* __restrict__ cc, float* __restrict__ md)
{
  const int tid = threadIdx.x;
  const int ch  = tid >> 7;            // which of 2 chunks
  const int t7  = tid & 127;
  const int rr  = t7 >> 2;             // row pair -> rows 2rr, 2rr+1
  const int qr  = t7 & 3;              // col quarter

  __shared__ float    ewS[2][4][N_], vS[2][4][N_];
  __shared__ ushort_t zS[2][4][N_], bS[2][4][N_], qS[2][4][N_], kS[2][4][N_];

  const int gcb = blockIdx.x*2;

  uint32_t pu[2][3];
#pragma unroll
  for (int it=0; it<2; it++){
    int slot = it*256 + tid;
    int sc = slot >> 8, s = (slot >> 6) & 3, d = slot & 63;
    int g = gcb + sc;
    int cx = g & (NC_-1), bh = g >> 4;
    int b = bh >> 4, h = bh & 15;
    size_t ap = (((size_t)(b*T_ + cx*L_ + s))*H_ + h)*64 + d;
    pu[it][0] = packed[ap*3]; pu[it][1] = packed[ap*3+1]; pu[it][2] = packed[ap*3+2];
  }

  float X0[16], X1[16], Z0[16], Z1[16];
#pragma unroll
  for (int i=0;i<16;i++){
    X0[i] = (qr*16+i == 2*rr)   ? 1.f : 0.f;
    X1[i] = (qr*16+i == 2*rr+1) ? 1.f : 0.f;
    Z0[i] = 0.f; Z1[i] = 0.f;
  }

  for (int tg = 0; tg < L_; tg += 4){
    __syncthreads();                    // prev group's readers done
#pragma unroll
    for (int it=0; it<2; it++){
      int slot = it*256 + tid;
      int sc = slot >> 8, s = (slot >> 6) & 3, d = slot & 63;
      ewS[sc][s][d] = __expf(bf2f(pu[it][0] & 0xffffu));
      zS[sc][s][d]  = (ushort_t)(pu[it][0] >> 16);
      bS[sc][s][d]  = (ushort_t)(pu[it][1] & 0xffffu);
      kS[sc][s][d]  = (ushort_t)(pu[it][1] >> 16);
      qS[sc][s][d]  = (ushort_t)(pu[it][2] & 0xffffu);
      vS[sc][s][d]  = bf2f(pu[it][2] >> 16);
    }
    if (tg + 4 < L_){
#pragma unroll
      for (int it=0; it<2; it++){
        int slot = it*256 + tid;
        int sc = slot >> 8, s = (slot >> 6) & 3, d = slot & 63;
        int g = gcb + sc;
        int cx = g & (NC_-1), bh = g >> 4;
        int b = bh >> 4, h = bh & 15;
        size_t ap = (((size_t)(b*T_ + cx*L_ + tg+4+s))*H_ + h)*64 + d;
        pu[it][0] = packed[ap*3]; pu[it][1] = packed[ap*3+1]; pu[it][2] = packed[ap*3+2];
      }
    }
    __syncthreads();                    // group visible
#pragma unroll 1
    for (int ss=0; ss<4; ss++){
      float zf[16];
      ldbf16x16(&zS[ch][ss][qr*16], zf);
      float sx0=0.f, sx1=0.f, sz0=0.f, sz1=0.f;
#pragma unroll
      for (int i=0;i<16;i++){
        sx0 = fmaf(X0[i], zf[i], sx0);
        sx1 = fmaf(X1[i], zf[i], sx1);
        sz0 = fmaf(Z0[i], zf[i], sz0);
        sz1 = fmaf(Z1[i], zf[i], sz1);
      }
      sx0 = quad_sum(sx0); sx1 = quad_sum(sx1);
      sz0 = quad_sum(sz0); sz1 = quad_sum(sz1);

      float ef[16], bf[16], qf[16], kf[16];
#pragma unroll
      for (int i4=0;i4<4;i4++)
        *(float4*)&ef[i4*4] = *(const float4*)&ewS[ch][ss][qr*16+i4*4];
      ldbf16x16(&bS[ch][ss][qr*16], bf);
      ldbf16x16(&qS[ch][ss][qr*16], qf);
      ldbf16x16(&kS[ch][ss][qr*16], kf);
      const float v0r = vS[ch][ss][2*rr];
      const float v1r = vS[ch][ss][2*rr+1];

      float m0=0.f,m1=0.f,d0=0.f,d1=0.f;
#pragma unroll
      for (int i=0;i<16;i++){
        float t;
        t = fmaf(X0[i], ef[i], sx0*bf[i]); X0[i]=t; m0 = fmaf(t, qf[i], m0);
        t = fmaf(X1[i], ef[i], sx1*bf[i]); X1[i]=t; m1 = fmaf(t, qf[i], m1);
        t = fmaf(Z0[i], ef[i], fmaf(sz0, bf[i], v0r*kf[i])); Z0[i]=t; d0 = fmaf(t, qf[i], d0);
        t = fmaf(Z1[i], ef[i], fmaf(sz1, bf[i], v1r*kf[i])); Z1[i]=t; d1 = fmaf(t, qf[i], d1);
      }
      m0 = quad_sum(m0); m1 = quad_sum(m1);
      d0 = quad_sum(d0); d1 = quad_sum(d1);
      const size_t mb = ((size_t)(gcb+ch)*L_ + tg+ss)*128;
      if      (qr == 0) md[mb + 2*rr]      = m0;
      else if (qr == 1) md[mb + 2*rr+1]    = m1;
      else if (qr == 2) md[mb + 64 + 2*rr]   = d0;
      else              md[mb + 64 + 2*rr+1] = d1;
    }
  }
  const size_t base = (size_t)(gcb+ch)*4096 + (size_t)(2*rr)*64 + qr*16;
#pragma unroll
  for (int i4=0;i4<4;i4++){
    *(float4*)&phi[base + i4*4]      = (float4){X0[i4*4+0],X0[i4*4+1],X0[i4*4+2],X0[i4*4+3]};
    *(float4*)&phi[base + 64 + i4*4] = (float4){X1[i4*4+0],X1[i4*4+1],X1[i4*4+2],X1[i4*4+3]};
    *(float4*)&cc [base + i4*4]      = (float4){Z0[i4*4+0],Z0[i4*4+1],Z0[i4*4+2],Z0[i4*4+3]};
    *(float4*)&cc [base + 64 + i4*4] = (float4){Z1[i4*4+0],Z1[i4*4+1],Z1[i4*4+2],Z1[i4*4+3]};
  }
}

// ---- pass 2: sequential chunk combine per (b,h), phi+cc both prefetched
__global__ __launch_bounds__(256) void chunk_state_kernel(
    const float* __restrict__ phi, const float* __restrict__ cc,
    float* __restrict__ sstart)
{
  const int bh = blockIdx.x;
  const int tid = threadIdx.x;
  const int rb = tid >> 4;
  const int cq = tid & 15;
  __shared__ float Sld[64][65];
  __shared__ float Fld[64][68];
  float acc[4][4];
#pragma unroll
  for (int m=0;m<4;m++)
#pragma unroll
    for (int i=0;i<4;i++) acc[m][i] = 0.f;
#pragma unroll
  for (int m=0;m<4;m++){
    float4 z4 = {0.f,0.f,0.f,0.f};
    *(float4*)&Sld[rb+16*m][cq*4] = z4;
  }
  const float* pc = phi + (size_t)bh*NC_*4096;
  const float* cb = cc  + (size_t)bh*NC_*4096;
  float4 pf[4], pcc[4];
#pragma unroll
  for (int p=0;p<4;p++) pf[p] = *(const float4*)&pc[(size_t)p*1024 + tid*4];
#pragma unroll
  for (int m=0;m<4;m++) pcc[m] = *(const float4*)&cb[(size_t)(rb+16*m)*64 + cq*4];

  for (int c=0;c<NC_;c++){
    __syncthreads();
#pragma unroll
    for (int p=0;p<4;p++){
      int f = p*1024 + tid*4;
      *(float4*)&Fld[f>>6][f&63] = pf[p];
    }
    float na[4][4];
#pragma unroll
    for (int m=0;m<4;m++){
      na[m][0]=pcc[m].x; na[m][1]=pcc[m].y; na[m][2]=pcc[m].z; na[m][3]=pcc[m].w;
    }
#pragma unroll
    for (int m=0;m<4;m++){
      float4 so = {acc[m][0],acc[m][1],acc[m][2],acc[m][3]};
      *(float4*)&sstart[(size_t)(bh*NC_+c)*4096 + (size_t)(rb+16*m)*64 + cq*4] = so;
    }
    if (c+1 < NC_){
#pragma unroll
      for (int p=0;p<4;p++) pf[p] = *(const float4*)&pc[(size_t)(c+1)*4096 + p*1024 + tid*4];
#pragma unroll
      for (int m=0;m<4;m++) pcc[m] = *(const float4*)&cb[(size_t)(c+1)*4096 + (size_t)(rb+16*m)*64 + cq*4];
    }
    __syncthreads();
#pragma unroll 1
    for (int k0=0;k0<64;k0+=4){
      float4 sr[4];
#pragma unroll
      for (int m=0;m<4;m++) sr[m] = *(const float4*)&Sld[rb+16*m][k0];
      const float4 f0 = *(const float4*)&Fld[k0+0][cq*4];
      const float4 f1 = *(const float4*)&Fld[k0+1][cq*4];
      const float4 f2 = *(const float4*)&Fld[k0+2][cq*4];
      const float4 f3 = *(const float4*)&Fld[k0+3][cq*4];
#pragma unroll
      for (int m=0;m<4;m++){
        na[m][0] = fmaf(sr[m].x, f0.x, na[m][0]); na[m][0] = fmaf(sr[m].y, f1.x, na[m][0]);
        na[m][0] = fmaf(sr[m].z, f2.x, na[m][0]); na[m][0] = fmaf(sr[m].w, f3.x, na[m][0]);
        na[m][1] = fmaf(sr[m].x, f0.y, na[m][1]); na[m][1] = fmaf(sr[m].y, f1.y, na[m][1]);
        na[m][1] = fmaf(sr[m].z, f2.y, na[m][1]); na[m][1] = fmaf(sr[m].w, f3.y, na[m][1]);
        na[m][2] = fmaf(sr[m].x, f0.z, na[m][2]); na[m][2] = fmaf(sr[m].y, f1.z, na[m][2]);
        na[m][2] = fmaf(sr[m].z, f2.z, na[m][2]); na[m][2] = fmaf(sr[m].w, f3.z, na[m][2]);
        na[m][3] = fmaf(sr[m].x, f0.w, na[m][3]); na[m][3] = fmaf(sr[m].y, f1.w, na[m][3]);
        na[m][3] = fmaf(sr[m].z, f2.w, na[m][3]); na[m][3] = fmaf(sr[m].w, f3.w, na[m][3]);
      }
    }
    __syncthreads();
#pragma unroll
    for (int m=0;m<4;m++){
      float4 so = {na[m][0],na[m][1],na[m][2],na[m][3]};
      *(float4*)&Sld[rb+16*m][cq*4] = so;
#pragma unroll
      for (int i=0;i<4;i++) acc[m][i] = na[m][i];
    }
  }
}

// ---- pass 3: o = S_start·m + d, epilogue, emit bf16 y
__global__ __launch_bounds__(256) void chunk_emit_kernel(
    const uint32_t* __restrict__ packed, const float* __restrict__ ratio,
    const float* __restrict__ g, const float* __restrict__ rk,
    const float* __restrict__ sstart, const float* __restrict__ md,
    ushort_t* __restrict__ y)
{
  const int blk = blockIdx.x;
  const int c  = blk & (NC_-1);
  const int bh = blk >> 4;
  const int b = bh >> 4, h = bh & 15;
  const int tid = threadIdx.x;
  const int v = tid & 63;
  const int tg = tid >> 6;

  float4 sr[16];
  const float4* sp = (const float4*)(sstart + (size_t)blk*4096 + (size_t)v*64);
#pragma unroll
  for (int f=0;f<16;f++) sr[f] = sp[f];
  const float sigrk = 1.f/(1.f+__expf(-rk[h*64+v]));

#pragma unroll 1
  for (int ss=0; ss<32; ss++){
    const int t = tg*32 + ss;
    const int token = b*T_ + c*L_ + t;
    const float* mrow = md + ((size_t)blk*L_ + t)*128;
    float o0=0.f,o1=0.f,o2=0.f,o3=0.f;
#pragma unroll
    for (int f=0;f<16;f+=4){
      float4 m0 = ((const float4*)mrow)[f+0];
      float4 m1 = ((const float4*)mrow)[f+1];
      float4 m2 = ((const float4*)mrow)[f+2];
      float4 m3 = ((const float4*)mrow)[f+3];
      o0 = fmaf(sr[f+0].x,m0.x, fmaf(sr[f+0].y,m0.y, fmaf(sr[f+0].z,m0.z, fmaf(sr[f+0].w,m0.w, o0))));
      o1 = fmaf(sr[f+1].x,m1.x, fmaf(sr[f+1].y,m1.y, fmaf(sr[f+1].z,m1.z, fmaf(sr[f+1].w,m1.w, o1))));
      o2 = fmaf(sr[f+2].x,m2.x, fmaf(sr[f+2].y,m2.y, fmaf(sr[f+2].z,m2.z, fmaf(sr[f+2].w,m2.w, o2))));
      o3 = fmaf(sr[f+3].x,m3.x, fmaf(sr[f+3].y,m3.y, fmaf(sr[f+3].z,m3.z, fmaf(sr[f+3].w,m3.w, o3))));
    }
    float o = ((o0+o1)+(o2+o3)) + mrow[64 + v];
    const float vt = bf2f(packed[(((size_t)token*H_ + h)*64 + v)*3 + 2] >> 16);
    const float uv = ratio[(size_t)token*H_ + h];
    const float gv = g[(size_t)token*C_ + h*64 + v];
    y[(size_t)token*C_ + h*64 + v] = f2bf((o*0.125f + vt*uv*sigrk)*gv);
  }
}

extern "C" void kernel_launch(void* const* d_in, const int* in_sizes, int n_in,
                              void* d_out, int out_size, void* d_ws, size_t ws_size,
                              hipStream_t stream)
{
  const float* residual = (const float*)d_in[0];
  const float* x    = (const float*)d_in[1];
  const float* x0   = (const float*)d_in[2];
  const float* dx0  = (const float*)d_in[3];
  const float* Wq   = (const float*)d_in[4];
  const float* Wk   = (const float*)d_in[5];
  const float* Wv   = (const float*)d_in[6];
  const float* Wpr  = (const float*)d_in[7];
  const float* x_q  = (const float*)d_in[8];
  const float* x_k  = (const float*)d_in[9];
  const float* x_v  = (const float*)d_in[10];
  const float* v0   = (const float*)d_in[11];
  const float* w0   = (const float*)d_in[12];
  const float* a0   = (const float*)d_in[13];
  const float* miss = (const float*)d_in[14];
  const float* rk   = (const float*)d_in[15];
  float* out = (float*)d_out;

  char* ws = (char*)d_ws;
  const size_t MB = (size_t)1 << 20;
  // phase A (pre-fuse):
  float*    q_m    = (float*)(ws + 0*MB);      // [0,64): q,k,v,vf f32
  float*    k_m    = (float*)(ws + 16*MB);
  float*    v_m    = (float*)(ws + 32*MB);
  float*    vf_m   = (float*)(ws + 48*MB);
  ushort_t* delb   = (ushort_t*)(ws + 64*MB);  // [64,96) bf16 deltas
  ushort_t* Ab     = (ushort_t*)(ws + 96*MB);  // [96,128): Aq,Ak,Av,Axf
  ushort_t* Xb     = (ushort_t*)(ws + 128*MB); // [128,136)
  ushort_t* Wb     = (ushort_t*)(ws + 136*MB); // [136,144): Wq,Wk,Wv,Wv
  // phase B (fuse onward):
  uint32_t* packed = (uint32_t*)(ws + 96*MB);  // [96,144) overlay Ab/Xb/Wb
  float*    g_m    = (float*)(ws + 144*MB);    // [144,160)
  ushort_t* Wpb    = (ushort_t*)(ws + 160*MB); // [160,162)
  ushort_t* missT  = (ushort_t*)(ws + 162*MB); // [162,163)
  float*    ratio  = (float*)(ws + 163*MB);    // 256KB
  // phase C (post-fuse, overlay dead q/k/v/vf + delb):
  float*    phi    = (float*)(ws + 0*MB);      // [0,8)
  float*    cc     = (float*)(ws + 16*MB);     // [16,24)
  float*    sstart = (float*)(ws + 32*MB);     // [32,40)
  ushort_t* yb     = (ushort_t*)(ws + 48*MB);  // [48,56) overlay vf_m
  float*    mdbuf  = (float*)(ws + 64*MB);     // [64,96) overlay delb

  ushort_t* Aq  = Ab + 0*(size_t)M_*C_;
  ushort_t* Ak  = Ab + 1*(size_t)M_*C_;
  ushort_t* Av  = Ab + 2*(size_t)M_*C_;
  ushort_t* Axf = Ab + 3*(size_t)M_*C_;

  dim3 blk(256);
  prep_all<<<4096 + 5*1024 + 64, blk, 0, stream>>>(
      x, x0, dx0, x_q, x_k, x_v, Wq, Wk, Wv, Wpr, miss,
      Aq, Ak, Av, Axf, Xb, Wb, Wpb, missT);
  mfma_gemm<<<dim3(C_/128, M_/128, 4), blk, 0, stream>>>(
      Ab, C_, (int64_t)M_*C_, Wb, C_, (int64_t)C_*C_,
      q_m, C_, (int64_t)M_*C_, 0, nullptr, C_);
  mfma_gemm<<<dim3(4*C_/128, M_/128, 1), blk, 0, stream>>>(
      Xb, C_, 0, missT, 128, 0, delb, 4*C_, 0, 1, nullptr, 128);
  fuse_kernel<<<M_*H_/4, blk, 0, stream>>>(q_m, k_m, v_m, vf_m, delb, x, w0, v0, a0, packed, g_m, ratio);
  chunk_mdp_kernel<<<B_*H_*NC_/2, blk, 0, stream>>>(packed, phi, cc, mdbuf);
  chunk_state_kernel<<<B_*H_, blk, 0, stream>>>(phi, cc, sstart);
  chunk_emit_kernel<<<B_*H_*NC_, blk, 0, stream>>>(packed, ratio, g_m, rk, sstart, mdbuf, yb);
  mfma_gemm<<<dim3(C_/128, M_/128, 1), blk, 0, stream>>>(
      yb, C_, 0, Wpb, C_, 0, out, C_, 0, 0, residual, C_);
}